// Round 1
// baseline (296.777 us; speedup 1.0000x reference)
//
#include <hip/hip_runtime.h>
#include <hip/hip_bf16.h>

#define DI __device__ __forceinline__

typedef __bf16 bf16x8 __attribute__((ext_vector_type(8)));
typedef float  f32x4  __attribute__((ext_vector_type(4)));

// B=4, T=32, S=256, E=512, H=8, D=64; M = B*T*S = 32768; SCALE = 8.

DI ushort f2bf(float f) {
  union { float f; unsigned u; } v; v.f = f;
  unsigned r = v.u + 0x7fffu + ((v.u >> 16) & 1u);
  return (ushort)(r >> 16);
}

DI f32x4 zero4() { f32x4 z; z[0] = 0.f; z[1] = 0.f; z[2] = 0.f; z[3] = 0.f; return z; }

union BF8U { ushort u[8]; bf16x8 v; };

// ---------------- weight transpose: W[k][n] f32 -> Wt[n][k] bf16 (4 matrices) --------
__global__ __launch_bounds__(256) void wtrans_kernel(
    const float* __restrict__ W0, const float* __restrict__ W1,
    const float* __restrict__ W2, const float* __restrict__ W3,
    ushort* __restrict__ out) {
  __shared__ float tile[64][65];
  const float* W = blockIdx.z == 0 ? W0 : blockIdx.z == 1 ? W1 : blockIdx.z == 2 ? W2 : W3;
  ushort* o = out + (size_t)blockIdx.z * 512 * 512;
  int k0 = blockIdx.x * 64, n0 = blockIdx.y * 64;
  int tid = threadIdx.x;
#pragma unroll
  for (int i = 0; i < 16; i++) {
    int idx = i * 256 + tid; int r = idx >> 6, c = idx & 63;
    tile[r][c] = W[(size_t)(k0 + r) * 512 + n0 + c];
  }
  __syncthreads();
#pragma unroll
  for (int i = 0; i < 16; i++) {
    int idx = i * 256 + tid; int r = idx >> 6, c = idx & 63;
    o[(size_t)(n0 + r) * 512 + k0 + c] = f2bf(tile[c][r]);
  }
}

// ---------------- GEMM: C[M][512] = A[M][512] * Bt^T + bias ------------------------
// A: fp32 (AF32=1, converted on stage) or bf16 (AF32=0). Bt is bf16 [N][K] (pre-transposed).
// OUTF32=1 -> fp32 out, else bf16 out. Tile 128x128, BK=64, 4 waves (2x2), 16x16x32 MFMA.
template <int AF32, int OUTF32>
__global__ __launch_bounds__(256) void gemm_kernel(
    const void* __restrict__ Ap, const ushort* __restrict__ Bt,
    const float* __restrict__ bias, void* __restrict__ Cp) {
  __shared__ __align__(16) char Alds[16384];  // [128][64] bf16, rows 128B, XOR swizzle
  __shared__ __align__(16) char Blds[16384];  // [128][64] bf16
  const float*  Af = (const float*)Ap;
  const ushort* Ah = (const ushort*)Ap;
  int tid = threadIdx.x, lane = tid & 63, wave = tid >> 6;
  int m0 = blockIdx.x * 128, n0 = blockIdx.y * 128;
  int wm = (wave >> 1) * 64, wn = (wave & 1) * 64;
  int srow = tid >> 3, skg = tid & 7;

  f32x4 acc[4][4];
#pragma unroll
  for (int i = 0; i < 4; i++)
#pragma unroll
    for (int j = 0; j < 4; j++) acc[i][j] = zero4();

  for (int k0 = 0; k0 < 512; k0 += 64) {
#pragma unroll
    for (int rr = 0; rr < 4; rr++) {
      int r = srow + rr * 32;
      BF8U av;
      if (AF32) {
        const float4* p = (const float4*)(Af + (size_t)(m0 + r) * 512 + k0 + skg * 8);
        float4 x = p[0], y = p[1];
        av.u[0] = f2bf(x.x); av.u[1] = f2bf(x.y); av.u[2] = f2bf(x.z); av.u[3] = f2bf(x.w);
        av.u[4] = f2bf(y.x); av.u[5] = f2bf(y.y); av.u[6] = f2bf(y.z); av.u[7] = f2bf(y.w);
      } else {
        av.v = *(const bf16x8*)(Ah + (size_t)(m0 + r) * 512 + k0 + skg * 8);
      }
      *(bf16x8*)(&Alds[(r * 128 + skg * 16) ^ ((r & 7) << 4)]) = av.v;
      bf16x8 bv = *(const bf16x8*)(Bt + (size_t)(n0 + r) * 512 + k0 + skg * 8);
      *(bf16x8*)(&Blds[(r * 128 + skg * 16) ^ ((r & 7) << 4)]) = bv;
    }
    __syncthreads();
#pragma unroll
    for (int ks = 0; ks < 2; ks++) {
      bf16x8 a[4], b[4];
#pragma unroll
      for (int i = 0; i < 4; i++) {
        int ra = wm + i * 16 + (lane & 15);
        a[i] = *(const bf16x8*)(&Alds[(ra * 128 + ks * 64 + (lane >> 4) * 16) ^ ((ra & 7) << 4)]);
        int rb = wn + i * 16 + (lane & 15);
        b[i] = *(const bf16x8*)(&Blds[(rb * 128 + ks * 64 + (lane >> 4) * 16) ^ ((rb & 7) << 4)]);
      }
#pragma unroll
      for (int i = 0; i < 4; i++)
#pragma unroll
        for (int j = 0; j < 4; j++)
          acc[i][j] = __builtin_amdgcn_mfma_f32_16x16x32_bf16(a[i], b[j], acc[i][j], 0, 0, 0);
    }
    __syncthreads();
  }
  // epilogue: D col = lane&15, row = (lane>>4)*4 + reg
#pragma unroll
  for (int j = 0; j < 4; j++) {
    int col = n0 + wn + j * 16 + (lane & 15);
    float bv = bias[col];
#pragma unroll
    for (int i = 0; i < 4; i++) {
#pragma unroll
      for (int r = 0; r < 4; r++) {
        int row = m0 + wm + i * 16 + (lane >> 4) * 4 + r;
        float val = acc[i][j][r] + bv;
        if (OUTF32) ((float*)Cp)[(size_t)row * 512 + col] = val;
        else        ((ushort*)Cp)[(size_t)row * 512 + col] = f2bf(val);
      }
    }
  }
}

// ---------------- attention per (bt, h): spike softmax, two-pass (max, then p & PV) ----
// Q/K/V bf16 in [m][f] layout (m = bt*256 + s, f = h*64 + d). 4 waves x 64 q-rows.
__global__ __launch_bounds__(256) void attn_kernel(
    const ushort* __restrict__ Q, const ushort* __restrict__ K,
    const ushort* __restrict__ V, const float* __restrict__ mw,
    ushort* __restrict__ att) {
  __shared__ __align__(16) char Vlds[32768];     // [64 d][256 k] bf16, rows 512B, swizzled
  __shared__ __align__(16) char Plds[4][8192];   // per-wave [64 q][64 k] bf16, rows 128B
  int tid = threadIdx.x, lane = tid & 63, wv = tid >> 6;
  int bt = blockIdx.x, h = blockIdx.y;
  size_t base = ((size_t)bt * 256) * 512 + h * 64;
  float c0 = mw[h] * mw[8 + h] * 0.125f;   // mod_w / SCALE  (temporal_sync cancels)

  // stage V transposed into LDS
#pragma unroll
  for (int i = 0; i < 8; i++) {
    int c = tid + i * 256; int r = c >> 3, dg = c & 7;
    BF8U u; u.v = *(const bf16x8*)(V + base + (size_t)r * 512 + dg * 8);
#pragma unroll
    for (int j = 0; j < 8; j++) {
      int d = dg * 8 + j;
      *(ushort*)(&Vlds[(d * 512 + r * 2) ^ ((d & 7) << 4)]) = u.u[j];
    }
  }
  // hoist Q fragments (A-operand: row = lane&15, k contiguous)
  bf16x8 qf[4][2];
#pragma unroll
  for (int qi = 0; qi < 4; qi++)
#pragma unroll
    for (int ds = 0; ds < 2; ds++)
      qf[qi][ds] = *(const bf16x8*)(Q + base + (size_t)(wv * 64 + qi * 16 + (lane & 15)) * 512 + ds * 32 + (lane >> 4) * 8);
  __syncthreads();

  // pass A: per-row max of c0 * (Q.K)
  float mx[4][4];
#pragma unroll
  for (int qi = 0; qi < 4; qi++)
#pragma unroll
    for (int r = 0; r < 4; r++) mx[qi][r] = -1e30f;
  for (int kt = 0; kt < 4; kt++) {
#pragma unroll
    for (int kf = 0; kf < 4; kf++) {
      int rk = kt * 64 + kf * 16 + (lane & 15);
      bf16x8 kb0 = *(const bf16x8*)(K + base + (size_t)rk * 512 + (lane >> 4) * 8);
      bf16x8 kb1 = *(const bf16x8*)(K + base + (size_t)rk * 512 + 32 + (lane >> 4) * 8);
#pragma unroll
      for (int qi = 0; qi < 4; qi++) {
        f32x4 s = zero4();
        s = __builtin_amdgcn_mfma_f32_16x16x32_bf16(qf[qi][0], kb0, s, 0, 0, 0);
        s = __builtin_amdgcn_mfma_f32_16x16x32_bf16(qf[qi][1], kb1, s, 0, 0, 0);
#pragma unroll
        for (int r = 0; r < 4; r++) mx[qi][r] = fmaxf(mx[qi][r], s[r] * c0);
      }
    }
  }
#pragma unroll
  for (int off = 1; off < 16; off <<= 1)
#pragma unroll
    for (int qi = 0; qi < 4; qi++)
#pragma unroll
      for (int r = 0; r < 4; r++)
        mx[qi][r] = fmaxf(mx[qi][r], __shfl_xor(mx[qi][r], off, 64));

  // pass B: p = sigmoid(5*(s - m)); accumulate row-sum and unnormalized P.V
  float sm[4][4];
#pragma unroll
  for (int qi = 0; qi < 4; qi++)
#pragma unroll
    for (int r = 0; r < 4; r++) sm[qi][r] = 0.f;
  f32x4 av[4][4];
#pragma unroll
  for (int qi = 0; qi < 4; qi++)
#pragma unroll
    for (int df = 0; df < 4; df++) av[qi][df] = zero4();

  for (int kt = 0; kt < 4; kt++) {
#pragma unroll
    for (int kf = 0; kf < 4; kf++) {
      int rk = kt * 64 + kf * 16 + (lane & 15);
      bf16x8 kb0 = *(const bf16x8*)(K + base + (size_t)rk * 512 + (lane >> 4) * 8);
      bf16x8 kb1 = *(const bf16x8*)(K + base + (size_t)rk * 512 + 32 + (lane >> 4) * 8);
#pragma unroll
      for (int qi = 0; qi < 4; qi++) {
        f32x4 s = zero4();
        s = __builtin_amdgcn_mfma_f32_16x16x32_bf16(qf[qi][0], kb0, s, 0, 0, 0);
        s = __builtin_amdgcn_mfma_f32_16x16x32_bf16(qf[qi][1], kb1, s, 0, 0, 0);
#pragma unroll
        for (int r = 0; r < 4; r++) {
          float p = 1.f / (1.f + __expf(-5.f * (s[r] * c0 - mx[qi][r])));
          sm[qi][r] += p;
          int row = qi * 16 + (lane >> 4) * 4 + r;
          int col = kf * 16 + (lane & 15);
          *(ushort*)(&Plds[wv][(row * 128 + col * 2) ^ ((row & 7) << 4)]) = f2bf(p);
        }
      }
    }
    __syncthreads();
#pragma unroll
    for (int ks = 0; ks < 2; ks++) {
      bf16x8 pa[4];
#pragma unroll
      for (int qi = 0; qi < 4; qi++) {
        int row = qi * 16 + (lane & 15);
        pa[qi] = *(const bf16x8*)(&Plds[wv][(row * 128 + ks * 64 + (lane >> 4) * 16) ^ ((row & 7) << 4)]);
      }
      bf16x8 vb[4];
#pragma unroll
      for (int df = 0; df < 4; df++) {
        int d = df * 16 + (lane & 15);
        vb[df] = *(const bf16x8*)(&Vlds[(d * 512 + kt * 128 + ks * 64 + (lane >> 4) * 16) ^ ((d & 7) << 4)]);
      }
#pragma unroll
      for (int qi = 0; qi < 4; qi++)
#pragma unroll
        for (int df = 0; df < 4; df++)
          av[qi][df] = __builtin_amdgcn_mfma_f32_16x16x32_bf16(pa[qi], vb[df], av[qi][df], 0, 0, 0);
    }
    __syncthreads();
  }

#pragma unroll
  for (int off = 1; off < 16; off <<= 1)
#pragma unroll
    for (int qi = 0; qi < 4; qi++)
#pragma unroll
      for (int r = 0; r < 4; r++)
        sm[qi][r] += __shfl_xor(sm[qi][r], off, 64);

#pragma unroll
  for (int qi = 0; qi < 4; qi++) {
    float rs[4];
#pragma unroll
    for (int r = 0; r < 4; r++) rs[r] = 1.f / (sm[qi][r] + 1e-8f);
#pragma unroll
    for (int df = 0; df < 4; df++) {
      int col = h * 64 + df * 16 + (lane & 15);
#pragma unroll
      for (int r = 0; r < 4; r++) {
        int row = bt * 256 + wv * 64 + qi * 16 + (lane >> 4) * 4 + r;
        att[(size_t)row * 512 + col] = f2bf(av[qi][df][r] * rs[r]);
      }
    }
  }
}

extern "C" void kernel_launch(void* const* d_in, const int* in_sizes, int n_in,
                              void* d_out, int out_size, void* d_ws, size_t ws_size,
                              hipStream_t stream) {
  (void)in_sizes; (void)n_in; (void)out_size; (void)ws_size;
  const float* qs  = (const float*)d_in[0];
  const float* ksn = (const float*)d_in[1];
  const float* vsn = (const float*)d_in[2];
  const float* Wq  = (const float*)d_in[3];
  const float* bq  = (const float*)d_in[4];
  const float* Wk  = (const float*)d_in[5];
  const float* bk  = (const float*)d_in[6];
  const float* Wv  = (const float*)d_in[7];
  const float* bv  = (const float*)d_in[8];
  const float* Wo  = (const float*)d_in[9];
  const float* bo  = (const float*)d_in[10];
  const float* mw  = (const float*)d_in[11];
  // d_in[12] = temporal_sync: constant along key axis -> cancels in spike softmax.

  char* ws = (char*)d_ws;
  ushort* Wt = (ushort*)ws;                                   // 4 * 512KiB bf16
  ushort* Qw = (ushort*)(ws + (size_t)(2u << 20));
  ushort* Kw = (ushort*)(ws + (size_t)(2u << 20) + 33554432u);
  ushort* Vw = (ushort*)(ws + (size_t)(2u << 20) + 2u * 33554432u);
  ushort* Aw = (ushort*)(ws + (size_t)(2u << 20) + 3u * 33554432u);

  wtrans_kernel<<<dim3(8, 8, 4), 256, 0, stream>>>(Wq, Wk, Wv, Wo, Wt);
  gemm_kernel<1, 0><<<dim3(256, 4), 256, 0, stream>>>(qs,  Wt + 0 * 262144, bq, Qw);
  gemm_kernel<1, 0><<<dim3(256, 4), 256, 0, stream>>>(ksn, Wt + 1 * 262144, bk, Kw);
  gemm_kernel<1, 0><<<dim3(256, 4), 256, 0, stream>>>(vsn, Wt + 2 * 262144, bv, Vw);
  attn_kernel<<<dim3(128, 8), 256, 0, stream>>>(Qw, Kw, Vw, mw, Aw);
  gemm_kernel<0, 1><<<dim3(256, 4), 256, 0, stream>>>(Aw, Wt + 3 * 262144, bo, d_out);
}

// Round 3
// 244.968 us; speedup vs baseline: 1.2115x; 1.2115x over previous
//
#include <hip/hip_runtime.h>
#include <hip/hip_bf16.h>

#define DI __device__ __forceinline__

typedef __bf16 bf16x8 __attribute__((ext_vector_type(8)));
typedef float  f32x4  __attribute__((ext_vector_type(4)));
typedef float  f32x16 __attribute__((ext_vector_type(16)));

// B=4, T=32, S=256, E=512, H=8, D=64; M = B*T*S = 32768; SCALE = 8.

DI ushort f2bf(float f) {
  union { float f; unsigned u; } v; v.f = f;
  unsigned r = v.u + 0x7fffu + ((v.u >> 16) & 1u);
  return (ushort)(r >> 16);
}

DI unsigned cvtpk2(float a, float b) {  // [bf16(a) | bf16(b)<<16], RNE
  unsigned r;
  asm("v_cvt_pk_bf16_f32 %0, %1, %2" : "=v"(r) : "v"(a), "v"(b));
  return r;
}

DI float rcpf(float x) {
  float r;
  asm("v_rcp_f32 %0, %1" : "=v"(r) : "v"(x));
  return r;
}

DI f32x4 zero4() { f32x4 z; z[0] = 0.f; z[1] = 0.f; z[2] = 0.f; z[3] = 0.f; return z; }

DI f32x16 zero16() {
  f32x16 z;
  for (int i = 0; i < 16; i++) z[i] = 0.f;
  return z;
}

union BF8U { ushort u[8]; unsigned d[4]; bf16x8 v; };

// ---------------- weight transpose: W[k][n] f32 -> Wt[n][k] bf16 (4 matrices) --------
__global__ __launch_bounds__(256) void wtrans_kernel(
    const float* __restrict__ W0, const float* __restrict__ W1,
    const float* __restrict__ W2, const float* __restrict__ W3,
    ushort* __restrict__ out) {
  __shared__ float tile[64][65];
  const float* W = blockIdx.z == 0 ? W0 : blockIdx.z == 1 ? W1 : blockIdx.z == 2 ? W2 : W3;
  ushort* o = out + (size_t)blockIdx.z * 512 * 512;
  int k0 = blockIdx.x * 64, n0 = blockIdx.y * 64;
  int tid = threadIdx.x;
#pragma unroll
  for (int i = 0; i < 16; i++) {
    int idx = i * 256 + tid; int r = idx >> 6, c = idx & 63;
    tile[r][c] = W[(size_t)(k0 + r) * 512 + n0 + c];
  }
  __syncthreads();
#pragma unroll
  for (int i = 0; i < 16; i++) {
    int idx = i * 256 + tid; int r = idx >> 6, c = idx & 63;
    o[(size_t)(n0 + r) * 512 + k0 + c] = f2bf(tile[c][r]);
  }
}

// ---------------- GEMM: C[M][512] = A[M][512] * Bt^T + bias ------------------------
// AF32: A is fp32 (converted on stage) else bf16. OUT: 0=bf16 [m][f], 1=f32 [m][f],
// 2=bf16 transposed Vt[(bt*512+f)][256] (packed ushort4 along s).
template <int AF32, int OUT>
__global__ __launch_bounds__(256) void gemm_kernel(
    const void* __restrict__ Ap, const ushort* __restrict__ Bt,
    const float* __restrict__ bias, void* __restrict__ Cp) {
  __shared__ __align__(16) char Alds[16384];  // [128][64] bf16, rows 128B, XOR swizzle
  __shared__ __align__(16) char Blds[16384];
  const float*  Af = (const float*)Ap;
  const ushort* Ah = (const ushort*)Ap;
  int tid = threadIdx.x, lane = tid & 63, wave = tid >> 6;
  int m0 = blockIdx.x * 128, n0 = blockIdx.y * 128;
  int wm = (wave >> 1) * 64, wn = (wave & 1) * 64;
  int srow = tid >> 3, skg = tid & 7;

  f32x4 acc[4][4];
#pragma unroll
  for (int i = 0; i < 4; i++)
#pragma unroll
    for (int j = 0; j < 4; j++) acc[i][j] = zero4();

  for (int k0 = 0; k0 < 512; k0 += 64) {
#pragma unroll
    for (int rr = 0; rr < 4; rr++) {
      int r = srow + rr * 32;
      BF8U av;
      if (AF32) {
        const float4* p = (const float4*)(Af + (size_t)(m0 + r) * 512 + k0 + skg * 8);
        float4 x = p[0], y = p[1];
        av.d[0] = cvtpk2(x.x, x.y); av.d[1] = cvtpk2(x.z, x.w);
        av.d[2] = cvtpk2(y.x, y.y); av.d[3] = cvtpk2(y.z, y.w);
      } else {
        av.v = *(const bf16x8*)(Ah + (size_t)(m0 + r) * 512 + k0 + skg * 8);
      }
      *(bf16x8*)(&Alds[(r * 128 + skg * 16) ^ ((r & 7) << 4)]) = av.v;
      bf16x8 bv = *(const bf16x8*)(Bt + (size_t)(n0 + r) * 512 + k0 + skg * 8);
      *(bf16x8*)(&Blds[(r * 128 + skg * 16) ^ ((r & 7) << 4)]) = bv;
    }
    __syncthreads();
#pragma unroll
    for (int ks = 0; ks < 2; ks++) {
      bf16x8 a[4], b[4];
#pragma unroll
      for (int i = 0; i < 4; i++) {
        int ra = wm + i * 16 + (lane & 15);
        a[i] = *(const bf16x8*)(&Alds[(ra * 128 + ks * 64 + (lane >> 4) * 16) ^ ((ra & 7) << 4)]);
        int rb = wn + i * 16 + (lane & 15);
        b[i] = *(const bf16x8*)(&Blds[(rb * 128 + ks * 64 + (lane >> 4) * 16) ^ ((rb & 7) << 4)]);
      }
#pragma unroll
      for (int i = 0; i < 4; i++)
#pragma unroll
        for (int j = 0; j < 4; j++)
          acc[i][j] = __builtin_amdgcn_mfma_f32_16x16x32_bf16(a[i], b[j], acc[i][j], 0, 0, 0);
    }
    __syncthreads();
  }
  // epilogue: D col = lane&15, row = (lane>>4)*4 + reg
#pragma unroll
  for (int j = 0; j < 4; j++) {
    int col = n0 + wn + j * 16 + (lane & 15);
    float bv = bias[col];
#pragma unroll
    for (int i = 0; i < 4; i++) {
      int row0 = m0 + wm + i * 16 + (lane >> 4) * 4;
      if (OUT == 2) {
        int btv = row0 >> 8, s = row0 & 255;
        ushort4 w;
        w.x = f2bf(acc[i][j][0] + bv); w.y = f2bf(acc[i][j][1] + bv);
        w.z = f2bf(acc[i][j][2] + bv); w.w = f2bf(acc[i][j][3] + bv);
        *(ushort4*)((ushort*)Cp + ((size_t)btv * 512 + col) * 256 + s) = w;
      } else {
#pragma unroll
        for (int r = 0; r < 4; r++) {
          float val = acc[i][j][r] + bv;
          if (OUT == 1) ((float*)Cp)[(size_t)(row0 + r) * 512 + col] = val;
          else          ((ushort*)Cp)[(size_t)(row0 + r) * 512 + col] = f2bf(val);
        }
      }
    }
  }
}

// ---------------- attention: LDS-free, barrier-free, 1 wave = 64 q rows --------------
// Swapped S^T = mfma(K, Q) (32x32x16): lane owns q = lane&31 column; k rows in regs.
// P packed to bf16 in-register, PV A-frags assembled via shfl_xor(32) + select.
// V consumed from pre-transposed Vt[(bt*512+f)][256].
__global__ __launch_bounds__(64) void attn_kernel(
    const ushort* __restrict__ Q, const ushort* __restrict__ K,
    const ushort* __restrict__ Vt, const float* __restrict__ mw,
    ushort* __restrict__ att) {
  int lane = threadIdx.x & 63;
  int lq = lane & 31, hi = lane >> 5;
  int bid = ((int)blockIdx.x & 7) * 512 + ((int)blockIdx.x >> 3);  // XCD-chunked swizzle
  int qq = bid & 3, h = (bid >> 2) & 7, bt = bid >> 5;
  const ushort* Qb = Q + ((size_t)bt * 256 + qq * 64) * 512 + h * 64;
  const ushort* Kb = K + ((size_t)bt * 256) * 512 + h * 64;
  const ushort* Vb = Vt + ((size_t)bt * 512 + h * 64) * 256;
  float c0 = mw[h] * mw[8 + h] * 0.125f;  // temporal_sync cancels in spike softmax

  // hoist Q as B-operand fragments: lane reads its own q row (q = lq)
  bf16x8 qf[2][4];
#pragma unroll
  for (int qj = 0; qj < 2; qj++)
#pragma unroll
    for (int ds = 0; ds < 4; ds++)
      qf[qj][ds] = *(const bf16x8*)(Qb + (size_t)(qj * 32 + lq) * 512 + ds * 16 + hi * 8);

  // ---- pass A: row max of c0 * (Q.K) ----
  float mx[2] = {-3.0e38f, -3.0e38f};
#pragma unroll 1
  for (int kt = 0; kt < 8; kt++) {
    bf16x8 kf[4];
#pragma unroll
    for (int ds = 0; ds < 4; ds++)
      kf[ds] = *(const bf16x8*)(Kb + (size_t)(kt * 32 + lq) * 512 + ds * 16 + hi * 8);
#pragma unroll
    for (int qj = 0; qj < 2; qj++) {
      f32x16 sT = zero16();
#pragma unroll
      for (int ds = 0; ds < 4; ds++)
        sT = __builtin_amdgcn_mfma_f32_32x32x16_bf16(kf[ds], qf[qj][ds], sT, 0, 0, 0);
#pragma unroll
      for (int r = 0; r < 16; r++) mx[qj] = fmaxf(mx[qj], sT[r] * c0);
    }
  }
#pragma unroll
  for (int qj = 0; qj < 2; qj++) mx[qj] = fmaxf(mx[qj], __shfl_xor(mx[qj], 32, 64));

  // ---- pass B: p = sigmoid(5*(s*c0 - mx)); accumulate row-sum and P.V ----
  float a5 = 5.f * c0;
  float m5[2] = {5.f * mx[0], 5.f * mx[1]};
  float sm[2] = {0.f, 0.f};
  f32x16 acc[2][2];
  acc[0][0] = zero16(); acc[0][1] = zero16(); acc[1][0] = zero16(); acc[1][1] = zero16();

#pragma unroll 1
  for (int kt = 0; kt < 8; kt++) {
    bf16x8 kf[4], vf[2][2];
#pragma unroll
    for (int ds = 0; ds < 4; ds++)
      kf[ds] = *(const bf16x8*)(Kb + (size_t)(kt * 32 + lq) * 512 + ds * 16 + hi * 8);
#pragma unroll
    for (int ks = 0; ks < 2; ks++)
#pragma unroll
      for (int df = 0; df < 2; df++)
        vf[ks][df] = *(const bf16x8*)(Vb + (size_t)(df * 32 + lq) * 256 + kt * 32 + ks * 16 + hi * 8);
#pragma unroll
    for (int qj = 0; qj < 2; qj++) {
      f32x16 sT = zero16();
#pragma unroll
      for (int ds = 0; ds < 4; ds++)
        sT = __builtin_amdgcn_mfma_f32_32x32x16_bf16(kf[ds], qf[qj][ds], sT, 0, 0, 0);
      unsigned pk[8];
#pragma unroll
      for (int i = 0; i < 8; i++) {
        float p0 = rcpf(1.f + __expf(m5[qj] - sT[2 * i] * a5));
        float p1 = rcpf(1.f + __expf(m5[qj] - sT[2 * i + 1] * a5));
        sm[qj] += p0 + p1;
        pk[i] = cvtpk2(p0, p1);
      }
      // reg r holds k = (r&3) + 8*(r>>2) + 4*hi (+32*kt). Assemble A-frags:
#pragma unroll
      for (int ks = 0; ks < 2; ks++) {
        int b = ks * 4;
        unsigned sa = (unsigned)__shfl_xor((int)pk[b + 0], 32, 64);
        unsigned sb = (unsigned)__shfl_xor((int)pk[b + 1], 32, 64);
        unsigned sc = (unsigned)__shfl_xor((int)pk[b + 2], 32, 64);
        unsigned sd = (unsigned)__shfl_xor((int)pk[b + 3], 32, 64);
        BF8U pa;
        pa.d[0] = hi ? sc : pk[b + 0];
        pa.d[1] = hi ? sd : pk[b + 1];
        pa.d[2] = hi ? pk[b + 2] : sa;
        pa.d[3] = hi ? pk[b + 3] : sb;
#pragma unroll
        for (int df = 0; df < 2; df++)
          acc[qj][df] = __builtin_amdgcn_mfma_f32_32x32x16_bf16(pa.v, vf[ks][df], acc[qj][df], 0, 0, 0);
      }
    }
  }

  // ---- epilogue: normalize by row-sum, write att[m][f] bf16 ----
#pragma unroll
  for (int qj = 0; qj < 2; qj++) sm[qj] += __shfl_xor(sm[qj], 32, 64);
  float rs[2] = {rcpf(sm[0] + 1e-8f), rcpf(sm[1] + 1e-8f)};
#pragma unroll
  for (int qj = 0; qj < 2; qj++) {
#pragma unroll
    for (int r = 0; r < 16; r++) {
      int ql = (r & 3) + 8 * (r >> 2) + 4 * hi;
      float rr = __shfl(rs[qj], ql, 64);
      size_t rowbase = ((size_t)bt * 256 + qq * 64 + qj * 32 + ql) * 512 + h * 64;
#pragma unroll
      for (int df = 0; df < 2; df++)
        att[rowbase + df * 32 + lq] = f2bf(acc[qj][df][r] * rr);
    }
  }
}

extern "C" void kernel_launch(void* const* d_in, const int* in_sizes, int n_in,
                              void* d_out, int out_size, void* d_ws, size_t ws_size,
                              hipStream_t stream) {
  (void)in_sizes; (void)n_in; (void)out_size; (void)ws_size;
  const float* qs  = (const float*)d_in[0];
  const float* ksn = (const float*)d_in[1];
  const float* vsn = (const float*)d_in[2];
  const float* Wq  = (const float*)d_in[3];
  const float* bq  = (const float*)d_in[4];
  const float* Wk  = (const float*)d_in[5];
  const float* bk  = (const float*)d_in[6];
  const float* Wv  = (const float*)d_in[7];
  const float* bv  = (const float*)d_in[8];
  const float* Wo  = (const float*)d_in[9];
  const float* bo  = (const float*)d_in[10];
  const float* mw  = (const float*)d_in[11];
  // d_in[12] = temporal_sync: constant along key axis -> cancels in spike softmax.

  char* ws = (char*)d_ws;
  ushort* Wt = (ushort*)ws;                                   // 4 * 512KiB bf16
  ushort* Qw = (ushort*)(ws + (size_t)(2u << 20));
  ushort* Kw = (ushort*)(ws + (size_t)(2u << 20) + 33554432u);
  ushort* Vt = (ushort*)(ws + (size_t)(2u << 20) + 2u * 33554432u);
  ushort* Aw = (ushort*)(ws + (size_t)(2u << 20) + 3u * 33554432u);

  wtrans_kernel<<<dim3(8, 8, 4), 256, 0, stream>>>(Wq, Wk, Wv, Wo, Wt);
  gemm_kernel<1, 0><<<dim3(256, 4), 256, 0, stream>>>(qs,  Wt + 0 * 262144, bq, Qw);
  gemm_kernel<1, 0><<<dim3(256, 4), 256, 0, stream>>>(ksn, Wt + 1 * 262144, bk, Kw);
  gemm_kernel<1, 2><<<dim3(256, 4), 256, 0, stream>>>(vsn, Wt + 2 * 262144, bv, Vt);
  attn_kernel<<<dim3(4096), 64, 0, stream>>>(Qw, Kw, Vt, mw, Aw);
  gemm_kernel<0, 1><<<dim3(256, 4), 256, 0, stream>>>(Aw, Wt + 3 * 262144, bo, d_out);
}

// Round 4
// 230.446 us; speedup vs baseline: 1.2878x; 1.0630x over previous
//
#include <hip/hip_runtime.h>
#include <hip/hip_bf16.h>

#define DI __device__ __forceinline__

typedef __bf16 bf16x8 __attribute__((ext_vector_type(8)));
typedef float  f32x4  __attribute__((ext_vector_type(4)));
typedef float  f32x16 __attribute__((ext_vector_type(16)));

// B=4, T=32, S=256, E=512, H=8, D=64; M = B*T*S = 32768; SCALE = 8.

DI ushort f2bf(float f) {
  union { float f; unsigned u; } v; v.f = f;
  unsigned r = v.u + 0x7fffu + ((v.u >> 16) & 1u);
  return (ushort)(r >> 16);
}

DI unsigned cvtpk2(float a, float b) {  // [bf16(a) | bf16(b)<<16], RNE
  unsigned r;
  asm("v_cvt_pk_bf16_f32 %0, %1, %2" : "=v"(r) : "v"(a), "v"(b));
  return r;
}

DI float rcpf(float x) {
  float r;
  asm("v_rcp_f32 %0, %1" : "=v"(r) : "v"(x));
  return r;
}

DI void gload_lds16(const void* g, void* lds) {
  __builtin_amdgcn_global_load_lds(
      (const __attribute__((address_space(1))) unsigned*)g,
      (__attribute__((address_space(3))) unsigned*)lds, 16, 0, 0);
}

DI f32x4 zero4() { f32x4 z; z[0] = 0.f; z[1] = 0.f; z[2] = 0.f; z[3] = 0.f; return z; }

DI f32x16 zero16() {
  f32x16 z;
  for (int i = 0; i < 16; i++) z[i] = 0.f;
  return z;
}

union BF8U { ushort u[8]; unsigned d[4]; bf16x8 v; };

// ---------------- weight transpose: W[k][n] f32 -> Wt[n][k] bf16 (4 matrices) --------
__global__ __launch_bounds__(256) void wtrans_kernel(
    const float* __restrict__ W0, const float* __restrict__ W1,
    const float* __restrict__ W2, const float* __restrict__ W3,
    ushort* __restrict__ out) {
  __shared__ float tile[64][65];
  const float* W = blockIdx.z == 0 ? W0 : blockIdx.z == 1 ? W1 : blockIdx.z == 2 ? W2 : W3;
  ushort* o = out + (size_t)blockIdx.z * 512 * 512;
  int k0 = blockIdx.x * 64, n0 = blockIdx.y * 64;
  int tid = threadIdx.x;
#pragma unroll
  for (int i = 0; i < 16; i++) {
    int idx = i * 256 + tid; int r = idx >> 6, c = idx & 63;
    tile[r][c] = W[(size_t)(k0 + r) * 512 + n0 + c];
  }
  __syncthreads();
#pragma unroll
  for (int i = 0; i < 16; i++) {
    int idx = i * 256 + tid; int r = idx >> 6, c = idx & 63;
    o[(size_t)(n0 + r) * 512 + k0 + c] = f2bf(tile[c][r]);
  }
}

// ---------------- GEMM: C[M][512] = A[M][512] * Bt^T + bias ------------------------
// AF32: A fp32 (converted on stage) else bf16. OUT: 0=bf16 [m][f], 1=f32 [m][f],
// 2=bf16 transposed Vt[(bt*512+f)][256]. 1D grid 1024, XCD-chunked swizzle so the
// 4 n-blocks sharing an A-panel run consecutively on one XCD (L2 A-reuse).
template <int AF32, int OUT>
__global__ __launch_bounds__(256) void gemm_kernel(
    const void* __restrict__ Ap, const ushort* __restrict__ Bt,
    const float* __restrict__ bias, void* __restrict__ Cp) {
  __shared__ __align__(16) char Alds[16384];  // [128][64] bf16, rows 128B, XOR swizzle
  __shared__ __align__(16) char Blds[16384];
  const float*  Af = (const float*)Ap;
  const ushort* Ah = (const ushort*)Ap;
  int tid = threadIdx.x, lane = tid & 63, wave = tid >> 6;
  int bl = ((int)blockIdx.x & 7) * 128 + ((int)blockIdx.x >> 3);
  int m0 = (bl >> 2) * 128, n0 = (bl & 3) * 128;
  int wm = (wave >> 1) * 64, wn = (wave & 1) * 64;
  int srow = tid >> 3, skg = tid & 7;

  f32x4 acc[4][4];
#pragma unroll
  for (int i = 0; i < 4; i++)
#pragma unroll
    for (int j = 0; j < 4; j++) acc[i][j] = zero4();

  for (int k0 = 0; k0 < 512; k0 += 64) {
#pragma unroll
    for (int rr = 0; rr < 4; rr++) {
      int r = srow + rr * 32;
      BF8U av;
      if (AF32) {
        const float4* p = (const float4*)(Af + (size_t)(m0 + r) * 512 + k0 + skg * 8);
        float4 x = p[0], y = p[1];
        av.d[0] = cvtpk2(x.x, x.y); av.d[1] = cvtpk2(x.z, x.w);
        av.d[2] = cvtpk2(y.x, y.y); av.d[3] = cvtpk2(y.z, y.w);
      } else {
        av.v = *(const bf16x8*)(Ah + (size_t)(m0 + r) * 512 + k0 + skg * 8);
      }
      *(bf16x8*)(&Alds[(r * 128 + skg * 16) ^ ((r & 7) << 4)]) = av.v;
      bf16x8 bv = *(const bf16x8*)(Bt + (size_t)(n0 + r) * 512 + k0 + skg * 8);
      *(bf16x8*)(&Blds[(r * 128 + skg * 16) ^ ((r & 7) << 4)]) = bv;
    }
    __syncthreads();
#pragma unroll
    for (int ks = 0; ks < 2; ks++) {
      bf16x8 a[4], b[4];
#pragma unroll
      for (int i = 0; i < 4; i++) {
        int ra = wm + i * 16 + (lane & 15);
        a[i] = *(const bf16x8*)(&Alds[(ra * 128 + ks * 64 + (lane >> 4) * 16) ^ ((ra & 7) << 4)]);
        int rb = wn + i * 16 + (lane & 15);
        b[i] = *(const bf16x8*)(&Blds[(rb * 128 + ks * 64 + (lane >> 4) * 16) ^ ((rb & 7) << 4)]);
      }
#pragma unroll
      for (int i = 0; i < 4; i++)
#pragma unroll
        for (int j = 0; j < 4; j++)
          acc[i][j] = __builtin_amdgcn_mfma_f32_16x16x32_bf16(a[i], b[j], acc[i][j], 0, 0, 0);
    }
    __syncthreads();
  }
  // epilogue: D col = lane&15, row = (lane>>4)*4 + reg
#pragma unroll
  for (int j = 0; j < 4; j++) {
    int col = n0 + wn + j * 16 + (lane & 15);
    float bv = bias[col];
#pragma unroll
    for (int i = 0; i < 4; i++) {
      int row0 = m0 + wm + i * 16 + (lane >> 4) * 4;
      if (OUT == 2) {
        int btv = row0 >> 8, s = row0 & 255;
        ushort4 w;
        w.x = f2bf(acc[i][j][0] + bv); w.y = f2bf(acc[i][j][1] + bv);
        w.z = f2bf(acc[i][j][2] + bv); w.w = f2bf(acc[i][j][3] + bv);
        *(ushort4*)((ushort*)Cp + ((size_t)btv * 512 + col) * 256 + s) = w;
      } else {
#pragma unroll
        for (int r = 0; r < 4; r++) {
          float val = acc[i][j][r] + bv;
          if (OUT == 1) ((float*)Cp)[(size_t)(row0 + r) * 512 + col] = val;
          else          ((ushort*)Cp)[(size_t)(row0 + r) * 512 + col] = f2bf(val);
        }
      }
    }
  }
}

// ---------------- attention: block = (bt,h), 4 waves x 64 q rows -------------------
// K and V staged ONCE into LDS via global_load_lds, laid out in exact fragment-read
// order so every ds_read is a conflict-free base + lane*16 b128. V staging issues
// after the K-barrier and drains at the pass-A/pass-B barrier (hidden under pass A).
// Swapped S^T = mfma(K,Q): lane owns q = lane&31; P packed bf16 in-register,
// PV A-frags assembled via shfl_xor(32) + select. temporal_sync cancels.
__global__ __launch_bounds__(256) void attn_kernel(
    const ushort* __restrict__ Q, const ushort* __restrict__ K,
    const ushort* __restrict__ Vt, const float* __restrict__ mw,
    ushort* __restrict__ att) {
  __shared__ __align__(16) char Klds[32768];  // [kt][ds][hi][lq] 16B chunks
  __shared__ __align__(16) char Vlds[32768];  // [kt][ks][df][hi][lq] 16B chunks
  int tid = threadIdx.x, lane = tid & 63, wv = tid >> 6;
  int lq = lane & 31, hi = lane >> 5;
  int b = blockIdx.x;          // 1024 = 128 bt x 8 h
  int h = b & 7, bt = b >> 3;
  const ushort* Qb = Q + ((size_t)bt * 256 + wv * 64) * 512 + h * 64;
  const ushort* Kb = K + ((size_t)bt * 256) * 512 + h * 64;
  const ushort* Vb = Vt + ((size_t)bt * 512 + h * 64) * 256;
  float c0 = mw[h] * mw[8 + h] * 0.125f;

  // stage K: 32 x 1KB instrs across 4 waves, LDS order == fragment-read order
#pragma unroll
  for (int i = 0; i < 8; i++) {
    int ci = (wv * 8 + i) * 64 + lane;
    int l2 = ci & 31, h2 = (ci >> 5) & 1, ds = (ci >> 6) & 3, kt = ci >> 8;
    gload_lds16(Kb + (size_t)(kt * 32 + l2) * 512 + ds * 16 + h2 * 8,
                &Klds[(wv * 8 + i) * 1024]);
  }
  // hoist Q as B-operand fragments (global, drains at first barrier)
  bf16x8 qf[2][4];
#pragma unroll
  for (int qj = 0; qj < 2; qj++)
#pragma unroll
    for (int ds = 0; ds < 4; ds++)
      qf[qj][ds] = *(const bf16x8*)(Qb + (size_t)(qj * 32 + lq) * 512 + ds * 16 + hi * 8);
  __syncthreads();

  // issue V staging now; it drains at the next barrier (hidden under pass A)
#pragma unroll
  for (int i = 0; i < 8; i++) {
    int ci = (wv * 8 + i) * 64 + lane;
    int l2 = ci & 31, h2 = (ci >> 5) & 1, df = (ci >> 6) & 1, ks = (ci >> 7) & 1, kt = ci >> 8;
    gload_lds16(Vb + (size_t)(df * 32 + l2) * 256 + kt * 32 + ks * 16 + h2 * 8,
                &Vlds[(wv * 8 + i) * 1024]);
  }

  // ---- pass A: row max of c0 * (Q.K), K from LDS ----
  float mx[2] = {-3.0e38f, -3.0e38f};
#pragma unroll 2
  for (int kt = 0; kt < 8; kt++) {
    bf16x8 kf[4];
#pragma unroll
    for (int ds = 0; ds < 4; ds++)
      kf[ds] = *(const bf16x8*)(&Klds[((kt * 4 + ds) * 2 + hi) * 512 + lq * 16]);
#pragma unroll
    for (int qj = 0; qj < 2; qj++) {
      f32x16 sT = zero16();
#pragma unroll
      for (int ds = 0; ds < 4; ds++)
        sT = __builtin_amdgcn_mfma_f32_32x32x16_bf16(kf[ds], qf[qj][ds], sT, 0, 0, 0);
#pragma unroll
      for (int r = 0; r < 16; r++) mx[qj] = fmaxf(mx[qj], sT[r] * c0);
    }
  }
#pragma unroll
  for (int qj = 0; qj < 2; qj++) mx[qj] = fmaxf(mx[qj], __shfl_xor(mx[qj], 32, 64));
  __syncthreads();   // V staged

  // ---- pass B: p = sigmoid(5*(s*c0 - mx)); row-sum and P.V ----
  float a5 = 5.f * c0;
  float m5[2] = {5.f * mx[0], 5.f * mx[1]};
  float sm[2] = {0.f, 0.f};
  f32x16 acc[2][2];
  acc[0][0] = zero16(); acc[0][1] = zero16(); acc[1][0] = zero16(); acc[1][1] = zero16();

#pragma unroll 2
  for (int kt = 0; kt < 8; kt++) {
    bf16x8 kf[4], vf[2][2];
#pragma unroll
    for (int ds = 0; ds < 4; ds++)
      kf[ds] = *(const bf16x8*)(&Klds[((kt * 4 + ds) * 2 + hi) * 512 + lq * 16]);
#pragma unroll
    for (int ks = 0; ks < 2; ks++)
#pragma unroll
      for (int df = 0; df < 2; df++)
        vf[ks][df] = *(const bf16x8*)(&Vlds[(((kt * 2 + ks) * 2 + df) * 2 + hi) * 512 + lq * 16]);
#pragma unroll
    for (int qj = 0; qj < 2; qj++) {
      f32x16 sT = zero16();
#pragma unroll
      for (int ds = 0; ds < 4; ds++)
        sT = __builtin_amdgcn_mfma_f32_32x32x16_bf16(kf[ds], qf[qj][ds], sT, 0, 0, 0);
      unsigned pk[8];
#pragma unroll
      for (int i = 0; i < 8; i++) {
        float p0 = rcpf(1.f + __expf(m5[qj] - sT[2 * i] * a5));
        float p1 = rcpf(1.f + __expf(m5[qj] - sT[2 * i + 1] * a5));
        sm[qj] += p0 + p1;
        pk[i] = cvtpk2(p0, p1);
      }
      // reg r holds k = (r&3) + 8*(r>>2) + 4*hi (+32*kt). Assemble A-frags:
#pragma unroll
      for (int ks = 0; ks < 2; ks++) {
        int bb = ks * 4;
        unsigned sa = (unsigned)__shfl_xor((int)pk[bb + 0], 32, 64);
        unsigned sb = (unsigned)__shfl_xor((int)pk[bb + 1], 32, 64);
        unsigned sc = (unsigned)__shfl_xor((int)pk[bb + 2], 32, 64);
        unsigned sd = (unsigned)__shfl_xor((int)pk[bb + 3], 32, 64);
        BF8U pa;
        pa.d[0] = hi ? sc : pk[bb + 0];
        pa.d[1] = hi ? sd : pk[bb + 1];
        pa.d[2] = hi ? pk[bb + 2] : sa;
        pa.d[3] = hi ? pk[bb + 3] : sb;
#pragma unroll
        for (int df = 0; df < 2; df++)
          acc[qj][df] = __builtin_amdgcn_mfma_f32_32x32x16_bf16(pa.v, vf[ks][df], acc[qj][df], 0, 0, 0);
      }
    }
  }

  // ---- epilogue: normalize by row-sum, write att[m][f] bf16 ----
#pragma unroll
  for (int qj = 0; qj < 2; qj++) sm[qj] += __shfl_xor(sm[qj], 32, 64);
  float rs[2] = {rcpf(sm[0] + 1e-8f), rcpf(sm[1] + 1e-8f)};
#pragma unroll
  for (int qj = 0; qj < 2; qj++) {
#pragma unroll
    for (int r = 0; r < 16; r++) {
      int ql = (r & 3) + 8 * (r >> 2) + 4 * hi;
      float rr = __shfl(rs[qj], ql, 64);
      size_t rowbase = ((size_t)bt * 256 + wv * 64 + qj * 32 + ql) * 512 + h * 64;
#pragma unroll
      for (int df = 0; df < 2; df++)
        att[rowbase + df * 32 + lq] = f2bf(acc[qj][df][r] * rr);
    }
  }
}

extern "C" void kernel_launch(void* const* d_in, const int* in_sizes, int n_in,
                              void* d_out, int out_size, void* d_ws, size_t ws_size,
                              hipStream_t stream) {
  (void)in_sizes; (void)n_in; (void)out_size; (void)ws_size;
  const float* qs  = (const float*)d_in[0];
  const float* ksn = (const float*)d_in[1];
  const float* vsn = (const float*)d_in[2];
  const float* Wq  = (const float*)d_in[3];
  const float* bq  = (const float*)d_in[4];
  const float* Wk  = (const float*)d_in[5];
  const float* bk  = (const float*)d_in[6];
  const float* Wv  = (const float*)d_in[7];
  const float* bv  = (const float*)d_in[8];
  const float* Wo  = (const float*)d_in[9];
  const float* bo  = (const float*)d_in[10];
  const float* mw  = (const float*)d_in[11];
  // d_in[12] = temporal_sync: constant along key axis -> cancels in spike softmax.

  char* ws = (char*)d_ws;
  ushort* Wt = (ushort*)ws;                                   // 4 * 512KiB bf16
  ushort* Qw = (ushort*)(ws + (size_t)(2u << 20));
  ushort* Kw = (ushort*)(ws + (size_t)(2u << 20) + 33554432u);
  ushort* Vt = (ushort*)(ws + (size_t)(2u << 20) + 2u * 33554432u);
  ushort* Aw = (ushort*)(ws + (size_t)(2u << 20) + 3u * 33554432u);

  wtrans_kernel<<<dim3(8, 8, 4), 256, 0, stream>>>(Wq, Wk, Wv, Wo, Wt);
  gemm_kernel<1, 0><<<dim3(1024), 256, 0, stream>>>(qs,  Wt + 0 * 262144, bq, Qw);
  gemm_kernel<1, 0><<<dim3(1024), 256, 0, stream>>>(ksn, Wt + 1 * 262144, bk, Kw);
  gemm_kernel<1, 2><<<dim3(1024), 256, 0, stream>>>(vsn, Wt + 2 * 262144, bv, Vt);
  attn_kernel<<<dim3(1024), 256, 0, stream>>>(Qw, Kw, Vt, mw, Aw);
  gemm_kernel<0, 1><<<dim3(1024), 256, 0, stream>>>(Aw, Wt + 3 * 262144, bo, d_out);
}